// Round 22
// baseline (103.483 us; speedup 1.0000x reference)
//
#include <hip/hip_runtime.h>
#include <hip/hip_fp16.h>
#include <hip/hip_bf16.h>
#include <cstdint>
#include <cstddef>

// Problem constants: B=8, T=4096, D=512, H=512
constexpr int Bb = 8, Tt = 4096, Dd = 512, Hh = 512;
constexpr int Mm = Bb * Tt;          // 32768 rows
constexpr int CHUNKS = 128;
constexpr int CLEN = Tt / CHUNKS;    // 32

typedef short short8 __attribute__((ext_vector_type(8)));
typedef float f32x4 __attribute__((ext_vector_type(4)));

#define BMT 128   // time-rows per block
#define BHT 64    // h-cols per block (small B panels: 4 gload issues/wave)
#define BKT 64

__device__ inline void gload_lds16(const void* g, void* lds) {
  __builtin_amdgcn_global_load_lds(
      (const __attribute__((address_space(1))) unsigned int*)g,
      (__attribute__((address_space(3))) unsigned int*)lds,
      16, 0, 0);
}

// HW RNE cvt (v_cvt path; bit-identical to integer RNE for normal floats)
__device__ inline unsigned short bf16c(float f) {
  __hip_bfloat16 h = __float2bfloat16(f);
  union { __hip_bfloat16 h; unsigned short u; } cv;
  cv.h = h;
  return cv.u;
}
__device__ inline uint2 pack4_cvt(const float* p) {
  uint2 hv;
  hv.x = (unsigned)bf16c(p[0]) | ((unsigned)bf16c(p[1]) << 16);
  hv.y = (unsigned)bf16c(p[2]) | ((unsigned)bf16c(p[3]) << 16);
  return hv;
}

// W -> bf16 RNE, concatenated rows: Wc[1024][512] (rows 0..511 Wz, 512.. Wh)
__global__ __launch_bounds__(256) void prep_w(
    const float* __restrict__ Wz, const float* __restrict__ Wh,
    unsigned short* __restrict__ Wc) {
  int j = blockIdx.x * 256 + threadIdx.x;
  const float* src = (j < 65536) ? (Wz + (size_t)j * 4)
                                 : (Wh + (size_t)(j - 65536) * 4);
  float4 w = *(const float4*)src;
  *(uint2*)(Wc + (size_t)j * 4) = pack4_cvt((const float*)&w);
}

__device__ inline void gates_c(float kv, float pv, float& a, float& v) {
  a = 1.f / (1.f + __expf(kv));
  float z = 1.f - a;
  float g = (pv >= 0.f) ? (pv + 0.5f) : 1.f / (1.f + __expf(-pv));
  v = z * g;
}

// 128x64 dual-GEMM + fused gates + chunk aggregates.
// Occupancy + staging balance: acc 64 regs, LDS 32KB -> (256,3) = 3 blocks/CU
// AND B-panel gloads cut 4x vs BHT=128 (R21's null: BMT=64 doubled B work).
// A reg-staged w/ one-tile prefetch; counted vmcnt keeps prefetch in flight.
__global__ __launch_bounds__(256, 3) void gemm_fused(
    const float* __restrict__ x, const unsigned short* __restrict__ Wc,
    const float* __restrict__ bz, const float* __restrict__ bh,
    unsigned int* __restrict__ av,
    float* __restrict__ aggA, float* __restrict__ aggH) {
  __shared__ __align__(16) char smem[32768];
  unsigned short* Abf = (unsigned short*)smem;             // [128*64] 16KB
  unsigned short* Bzf = (unsigned short*)(smem + 16384);   // [64*64]   8KB
  unsigned short* Bhf = (unsigned short*)(smem + 24576);   // [64*64]   8KB
  float* AsL = (float*)smem;                               // [32][64]  8KB alias
  float* HsL = (float*)(smem + 8192);                      // [32][64]  8KB alias

  const int tid = threadIdx.x;
  const int lane = tid & 63, wid = tid >> 6;
  // XCD-aware bijective swizzle (2048 % 8 == 0): the 8 hn-blocks of one bm
  // panel are dispatch-adjacent within an XCD -> x panel L2-hits after first.
  int swz = (blockIdx.x & 7) * 256 + (blockIdx.x >> 3);
  const int bm = swz >> 3, hn = swz & 7;
  const int row0 = bm * BMT, h0 = hn * BHT;

  const int wr = (wid >> 1) * 64, hc = (wid & 1) * 32;  // wave sub-tile 64x32
  const int fr = lane & 15, kg = lane >> 4;

  // gload (B): wave covers 8 rows x 64 cols per issue; pre-swizzled source slot
  const int r8 = lane >> 3;
  const int c8 = ((lane & 7) ^ r8) * 8;
  // fragment-read swizzled slots
  const int fr7 = lane & 7;
  const int sk0 = (kg ^ fr7) * 8;
  const int sk1 = ((kg + 4) ^ fr7) * 8;

  f32x4 ak[4][2], ap[4][2];
#pragma unroll
  for (int i = 0; i < 4; ++i)
#pragma unroll
    for (int j = 0; j < 2; ++j) { ak[i][j] = (f32x4)0.f; ap[i][j] = (f32x4)0.f; }

  // prologue: load x(0) into regs (128 rows x 64 cols fp32 = 8 float4/thread)
  float4 avx[8];
#pragma unroll
  for (int i = 0; i < 8; ++i) {
    int f = i * 256 + tid;
    avx[i] = *(const float4*)(x + (size_t)(row0 + (f >> 4)) * Dd + (f & 15) * 4);
  }

  for (int k0 = 0; k0 < Dd; k0 += BKT) {
    __syncthreads();  // #1: prev iter's fragment reads done
    // B: async global->LDS (bf16, pre-swizzled source); 64 rows per panel
#pragma unroll
    for (int i = 0; i < 2; ++i) {
      int rw = wid * 16 + i * 8;
      gload_lds16(Wc + (size_t)(h0 + rw + r8) * Dd + k0 + c8, &Bzf[rw * BKT]);
      gload_lds16(Wc + (size_t)(512 + h0 + rw + r8) * Dd + k0 + c8, &Bhf[rw * BKT]);
    }
    // A: HW cvt to bf16, swizzled ds_write (8B granules)
#pragma unroll
    for (int i = 0; i < 8; ++i) {
      int f = i * 256 + tid;
      int r = f >> 4;
      uint2 hv = pack4_cvt((const float*)&avx[i]);
      int soff = ((((f & 15) >> 1) ^ (r & 7)) * 8) + (f & 1) * 4;
      *(uint2*)&Abf[r * BKT + soff] = hv;
    }
    asm volatile("" ::: "memory");  // fence: prefetch issues AFTER B gloads
    if (k0 + BKT < Dd) {
      // prefetch x(t+1); latency hides under this tile's MFMA section
#pragma unroll
      for (int i = 0; i < 8; ++i) {
        int f = i * 256 + tid;
        avx[i] = *(const float4*)(x + (size_t)(row0 + (f >> 4)) * Dd + (k0 + BKT) + (f & 15) * 4);
      }
      // 12 outstanding: 4 oldest = B gloads (must land), 8 newest = avx fly on
      asm volatile("s_waitcnt vmcnt(8) lgkmcnt(0)" ::: "memory");
    } else {
      asm volatile("s_waitcnt vmcnt(0) lgkmcnt(0)" ::: "memory");
    }
    asm volatile("s_barrier" ::: "memory");  // #2

#pragma unroll
    for (int ks = 0; ks < 2; ++ks) {
      const int sk = ks ? sk1 : sk0;
      short8 fa[4], fz[2], fh[2];
#pragma unroll
      for (int mi = 0; mi < 4; ++mi)
        fa[mi] = *(const short8*)&Abf[(wr + mi * 16 + fr) * BKT + sk];
#pragma unroll
      for (int ni = 0; ni < 2; ++ni) {
        fz[ni] = *(const short8*)&Bzf[(hc + ni * 16 + fr) * BKT + sk];
        fh[ni] = *(const short8*)&Bhf[(hc + ni * 16 + fr) * BKT + sk];
      }
#pragma unroll
      for (int mi = 0; mi < 4; ++mi)
#pragma unroll
        for (int ni = 0; ni < 2; ++ni) {
          ak[mi][ni] = __builtin_amdgcn_mfma_f32_16x16x32_bf16(fa[mi], fz[ni], ak[mi][ni], 0, 0, 0);
          ap[mi][ni] = __builtin_amdgcn_mfma_f32_16x16x32_bf16(fa[mi], fh[ni], ap[mi][ni], 0, 0, 0);
        }
    }
  }

  // ---- Fused epilogue ----
  __syncthreads();   // staging reads complete; smem reusable for As/Hs

  // C/D layout: col=lane&15 (fr), row=(lane>>4)*4+j (kg,j)
#pragma unroll
  for (int ni = 0; ni < 2; ++ni) {
    int colG = h0 + hc + ni * 16 + fr;
    float bzv = bz[colG];
    float bhv = bh[colG];
    int cl = hc + ni * 16 + fr;                 // 0..63
#pragma unroll
    for (int mi = 0; mi < 4; ++mi) {
      float A4 = 1.f, H4 = 0.f;
#pragma unroll
      for (int j = 0; j < 4; ++j) {
        float a, v;
        gates_c(ak[mi][ni][j] + bzv, ap[mi][ni][j] + bhv, a, v);
        int row = row0 + wr + mi * 16 + kg * 4 + j;
        unsigned int u = (unsigned int)__half_as_ushort(__float2half_rn(a)) |
                         ((unsigned int)__half_as_ushort(__float2half_rn(v)) << 16);
        av[(size_t)row * Hh + colG] = u;
        H4 = fmaf(a, H4, v);     // 4-row segment scan
        A4 *= a;
      }
      int srow = (wr >> 2) + mi * 4 + kg;       // 0..31
      AsL[srow * BHT + cl] = A4;
      HsL[srow * BHT + cl] = H4;
    }
  }
  __syncthreads();

  // fold 8 segments -> 1 chunk (32 rows); 4 chunks x 64 cols = 256 outputs
  const int b = row0 >> 12;
  const int cbase = (row0 & 4095) >> 5;
  {
    int chunk = tid >> 6, cl = tid & 63;        // 256 threads = 256 outputs
    float A = 1.f, H = 0.f;
#pragma unroll
    for (int s = 0; s < 8; ++s) {
      int srow = chunk * 8 + s;
      float As = AsL[srow * BHT + cl];
      float Hs = HsL[srow * BHT + cl];
      H = fmaf(As, H, Hs);
      A *= As;
    }
    size_t idx = ((size_t)b * CHUNKS + cbase + chunk) * Hh + h0 + cl;
    aggA[idx] = A;
    aggH[idx] = H;
  }
}

// Kogge-Stone scan over chunk aggregates (affine composition).
__global__ __launch_bounds__(256) void scan_carry_ks(
    const float* __restrict__ aggA, const float* __restrict__ aggH,
    const float* __restrict__ h0, float* __restrict__ carry) {
  __shared__ float As[256], Hs[256];
  const int tid = threadIdx.x;
  const int c = tid & 127;
  const int gch = blockIdx.x * 2 + (tid >> 7);   // 0..B*H-1
  const int b = gch >> 9, h = gch & 511;
  size_t base = (size_t)b * CHUNKS * Hh + h;
  float A = aggA[base + (size_t)c * Hh];
  float H = aggH[base + (size_t)c * Hh];
  As[tid] = A; Hs[tid] = H;
  __syncthreads();
#pragma unroll
  for (int s = 1; s < 128; s <<= 1) {
    float Al = 1.f, Hl = 0.f;
    const bool act = (c >= s);
    if (act) { Al = As[tid - s]; Hl = Hs[tid - s]; }
    __syncthreads();
    if (act) {
      H = fmaf(A, Hl, H);
      A = A * Al;
      As[tid] = A; Hs[tid] = H;
    }
    __syncthreads();
  }
  float hv = h0[(size_t)b * Hh + h];
  float g0 = (hv >= 0.f) ? (hv + 0.5f) : 1.f / (1.f + __expf(-hv));  // g(h0)
  float cr;
  if (c == 0) cr = g0;
  else cr = fmaf(As[tid - 1], g0, Hs[tid - 1]);
  carry[base + (size_t)c * Hh] = cr;
}

// Apply carry: read packed (a,v), write final h (fp32) to d_out.
__global__ __launch_bounds__(512) void scan_apply_av(
    const unsigned int* __restrict__ av, const float* __restrict__ carry,
    float* __restrict__ out) {
  const int h = threadIdx.x;
  const int bc = blockIdx.x;
  const int b = bc >> 7, c = bc & 127;
  float hp = carry[(size_t)bc * Hh + h];
  size_t base = ((size_t)b * Tt + (size_t)c * CLEN) * Hh + h;
#pragma unroll
  for (int i = 0; i < CLEN; ++i) {
    size_t idx = base + (size_t)i * Hh;
    unsigned int u = av[idx];
    float a = __half2float(__ushort_as_half((unsigned short)(u & 0xFFFFu)));
    float v = __half2float(__ushort_as_half((unsigned short)(u >> 16)));
    hp = fmaf(a, hp, v);
    out[idx] = hp;
  }
}

extern "C" void kernel_launch(void* const* d_in, const int* in_sizes, int n_in,
                              void* d_out, int out_size, void* d_ws, size_t ws_size,
                              hipStream_t stream) {
  const float* x  = (const float*)d_in[0];
  const float* h0 = (const float*)d_in[1];
  const float* Wz = (const float*)d_in[2];
  const float* bz = (const float*)d_in[3];
  const float* Wh = (const float*)d_in[4];
  const float* bh = (const float*)d_in[5];
  float* out = (float*)d_out;

  char* w = (char*)d_ws;
  unsigned int* avb    = (unsigned int*)w;                 // 64 MB packed (a,v)
  unsigned short* Wc   = (unsigned short*)(w + 67108864);  // 1 MB
  float* aggA          = (float*)(w + 68157440);           // 2 MB
  float* aggH          = (float*)(w + 70254592);           // 2 MB
  float* carry         = (float*)(w + 72351744);           // 2 MB (end 74448896)

  const int grid = (Mm / BMT) * (Hh / BHT);  // 256 * 8 = 2048
  prep_w<<<512, 256, 0, stream>>>(Wz, Wh, Wc);
  gemm_fused<<<grid, 256, 0, stream>>>(x, Wc, bz, bh, avb, aggA, aggH);
  scan_carry_ks<<<(Bb * Hh) / 2, 256, 0, stream>>>(aggA, aggH, h0, carry);
  scan_apply_av<<<Bb * CHUNKS, 512, 0, stream>>>(avb, carry, out);
}

// Round 23
// 100.414 us; speedup vs baseline: 1.0306x; 1.0306x over previous
//
#include <hip/hip_runtime.h>
#include <hip/hip_fp16.h>
#include <cstdint>
#include <cstddef>

// Problem constants: B=8, T=4096, D=512, H=512
constexpr int Bb = 8, Tt = 4096, Dd = 512, Hh = 512;
constexpr int Mm = Bb * Tt;          // 32768 rows
constexpr int CHUNKS = 128;
constexpr int CLEN = Tt / CHUNKS;    // 32

typedef short short8 __attribute__((ext_vector_type(8)));
typedef float f32x4 __attribute__((ext_vector_type(4)));

#define BMT 128   // time-rows per block
#define BHT 128   // h-cols per block
#define BKT 64

__device__ inline void gload_lds16(const void* g, void* lds) {
  __builtin_amdgcn_global_load_lds(
      (const __attribute__((address_space(1))) unsigned int*)g,
      (__attribute__((address_space(3))) unsigned int*)lds,
      16, 0, 0);
}

__device__ inline unsigned short bf16_rne(float f) {
  unsigned int u = __float_as_uint(f);
  unsigned int r = (u + 0x7FFFu + ((u >> 16) & 1u)) >> 16;
  return (unsigned short)r;
}
__device__ inline uint2 pack4_bf16(const float* p) {
  uint2 hv;
  hv.x = (unsigned)bf16_rne(p[0]) | ((unsigned)bf16_rne(p[1]) << 16);
  hv.y = (unsigned)bf16_rne(p[2]) | ((unsigned)bf16_rne(p[3]) << 16);
  return hv;
}

// W -> bf16 RNE, concatenated rows: Wc[1024][512] (rows 0..511 Wz, 512.. Wh)
__global__ __launch_bounds__(256) void prep_w(
    const float* __restrict__ Wz, const float* __restrict__ Wh,
    unsigned short* __restrict__ Wc) {
  int j = blockIdx.x * 256 + threadIdx.x;
  const float* src = (j < 65536) ? (Wz + (size_t)j * 4)
                                 : (Wh + (size_t)(j - 65536) * 4);
  float4 w = *(const float4*)src;
  *(uint2*)(Wc + (size_t)j * 4) = pack4_bf16((const float*)&w);
}

__device__ inline void gates_c(float kv, float pv, float& a, float& v) {
  a = 1.f / (1.f + __expf(kv));
  float z = 1.f - a;
  float g = (pv >= 0.f) ? (pv + 0.5f) : 1.f / (1.f + __expf(-pv));
  v = z * g;
}

// Best-measured config (R16, 100.2us total): 2-phase 128x128 dual-GEMM +
// fused gates + chunk aggregates.  A: x fp32 -> regs -> bf16 RNE -> swizzled
// ds_write (no prep_x pass).  B: global_load_lds, pre-swizzled source (T2).
// launch_bounds(256,2): (256,3) spills the 32-acc file (R13, 3.5x regression).
// Tile-shape search closed: (128,128,2bl)=75-77us beats (64,128,3bl)=77.8,
// (128,64,3bl)=85, 256-tile 8-phase=88-93.  Residual gap to floor is the
// 2-phase barrier drain (m233 structural).
__global__ __launch_bounds__(256, 2) void gemm_fused(
    const float* __restrict__ x, const unsigned short* __restrict__ Wc,
    const float* __restrict__ bz, const float* __restrict__ bh,
    unsigned int* __restrict__ av,
    float* __restrict__ aggA, float* __restrict__ aggH) {
  __shared__ __align__(16) char smem[49152];
  unsigned short* Abf = (unsigned short*)smem;             // [128*64] 16KB
  unsigned short* Bzf = (unsigned short*)(smem + 16384);   // Wz panel 16KB
  unsigned short* Bhf = (unsigned short*)(smem + 32768);   // Wh panel 16KB
  float* AsL = (float*)smem;                               // [32][128] alias
  float* HsL = (float*)(smem + 16384);                     // [32][128] alias

  const int tid = threadIdx.x;
  const int lane = tid & 63, wid = tid >> 6;
  // XCD-aware bijective swizzle (1024 % 8 == 0): hn-blocks of one bm panel
  // are dispatch-adjacent within an XCD -> x panel L2-hits after first touch.
  int swz = (blockIdx.x & 7) * 128 + (blockIdx.x >> 3);
  const int bm = swz >> 2, hn = swz & 3;
  const int row0 = bm * BMT, h0 = hn * BHT;

  const int wr = (wid >> 1) * 64, hc = (wid & 1) * 64;  // wave sub-tile
  const int fr = lane & 15, kg = lane >> 4;

  // gload (B): wave covers 8 rows x 64 cols per issue; pre-swizzled source slot
  const int r8 = lane >> 3;
  const int c8 = ((lane & 7) ^ r8) * 8;
  // fragment-read swizzled slots
  const int fr7 = lane & 7;
  const int sk0 = (kg ^ fr7) * 8;
  const int sk1 = ((kg + 4) ^ fr7) * 8;

  f32x4 ak[4][4], ap[4][4];
#pragma unroll
  for (int i = 0; i < 4; ++i)
#pragma unroll
    for (int j = 0; j < 4; ++j) { ak[i][j] = (f32x4)0.f; ap[i][j] = (f32x4)0.f; }

  for (int k0 = 0; k0 < Dd; k0 += BKT) {
    // A: global fp32 -> regs (issued before barrier; latency overlaps tail)
    float4 avx[8];
#pragma unroll
    for (int i = 0; i < 8; ++i) {
      int f = i * 256 + tid;
      avx[i] = *(const float4*)(x + (size_t)(row0 + (f >> 4)) * Dd + k0 + (f & 15) * 4);
    }
    __syncthreads();  // previous iter's fragment reads complete
    // B: async global->LDS (bf16, pre-swizzled source)
#pragma unroll
    for (int i = 0; i < 4; ++i) {
      int rw = wid * 32 + i * 8;
      gload_lds16(Wc + (size_t)(h0 + rw + r8) * Dd + k0 + c8, &Bzf[rw * BKT]);
      gload_lds16(Wc + (size_t)(512 + h0 + rw + r8) * Dd + k0 + c8, &Bhf[rw * BKT]);
    }
    // A: cvt to bf16, swizzled ds_write (8B granules)
#pragma unroll
    for (int i = 0; i < 8; ++i) {
      int f = i * 256 + tid;
      int r = f >> 4;
      uint2 hv = pack4_bf16((const float*)&avx[i]);
      int soff = ((((f & 15) >> 1) ^ (r & 7)) * 8) + (f & 1) * 4;
      *(uint2*)&Abf[r * BKT + soff] = hv;
    }
    __syncthreads();  // drains vmcnt (gload) + lgkm (ds_write)

#pragma unroll
    for (int ks = 0; ks < 2; ++ks) {
      const int sk = ks ? sk1 : sk0;
      short8 fa[4], fz[4], fh[4];
#pragma unroll
      for (int mi = 0; mi < 4; ++mi)
        fa[mi] = *(const short8*)&Abf[(wr + mi * 16 + fr) * BKT + sk];
#pragma unroll
      for (int ni = 0; ni < 4; ++ni) {
        fz[ni] = *(const short8*)&Bzf[(hc + ni * 16 + fr) * BKT + sk];
        fh[ni] = *(const short8*)&Bhf[(hc + ni * 16 + fr) * BKT + sk];
      }
#pragma unroll
      for (int mi = 0; mi < 4; ++mi)
#pragma unroll
        for (int ni = 0; ni < 4; ++ni) {
          ak[mi][ni] = __builtin_amdgcn_mfma_f32_16x16x32_bf16(fa[mi], fz[ni], ak[mi][ni], 0, 0, 0);
          ap[mi][ni] = __builtin_amdgcn_mfma_f32_16x16x32_bf16(fa[mi], fh[ni], ap[mi][ni], 0, 0, 0);
        }
    }
  }

  // ---- Fused epilogue ----
  __syncthreads();   // staging reads complete; smem reusable for As/Hs

  // C/D layout: col=lane&15 (fr), row=(lane>>4)*4+j (kg,j)
#pragma unroll
  for (int ni = 0; ni < 4; ++ni) {
    int colG = h0 + hc + ni * 16 + fr;
    float bzv = bz[colG];
    float bhv = bh[colG];
    int cl = hc + ni * 16 + fr;
#pragma unroll
    for (int mi = 0; mi < 4; ++mi) {
      float A4 = 1.f, H4 = 0.f;
#pragma unroll
      for (int j = 0; j < 4; ++j) {
        float a, v;
        gates_c(ak[mi][ni][j] + bzv, ap[mi][ni][j] + bhv, a, v);
        int row = row0 + wr + mi * 16 + kg * 4 + j;
        unsigned int u = (unsigned int)__half_as_ushort(__float2half_rn(a)) |
                         ((unsigned int)__half_as_ushort(__float2half_rn(v)) << 16);
        av[(size_t)row * Hh + colG] = u;
        H4 = fmaf(a, H4, v);     // 4-row segment scan
        A4 *= a;
      }
      int srow = (wr >> 2) + mi * 4 + kg;   // 0..31
      AsL[srow * BHT + cl] = A4;
      HsL[srow * BHT + cl] = H4;
    }
  }
  __syncthreads();

  // fold 8 segments -> 1 chunk (32 rows); 4 chunks x 128 cols = 512 outputs
  const int b = row0 >> 12;
  const int cbase = (row0 & 4095) >> 5;
#pragma unroll
  for (int p0 = 0; p0 < 2; ++p0) {
    int p = p0 * 256 + tid;
    int chunk = p >> 7, cl = p & 127;
    float A = 1.f, H = 0.f;
#pragma unroll
    for (int s = 0; s < 8; ++s) {
      int srow = chunk * 8 + s;
      float As = AsL[srow * BHT + cl];
      float Hs = HsL[srow * BHT + cl];
      H = fmaf(As, H, Hs);
      A *= As;
    }
    size_t idx = ((size_t)b * CHUNKS + cbase + chunk) * Hh + h0 + cl;
    aggA[idx] = A;
    aggH[idx] = H;
  }
}

// Kogge-Stone scan over chunk aggregates (affine composition).
__global__ __launch_bounds__(256) void scan_carry_ks(
    const float* __restrict__ aggA, const float* __restrict__ aggH,
    const float* __restrict__ h0, float* __restrict__ carry) {
  __shared__ float As[256], Hs[256];
  const int tid = threadIdx.x;
  const int c = tid & 127;
  const int gch = blockIdx.x * 2 + (tid >> 7);   // 0..B*H-1
  const int b = gch >> 9, h = gch & 511;
  size_t base = (size_t)b * CHUNKS * Hh + h;
  float A = aggA[base + (size_t)c * Hh];
  float H = aggH[base + (size_t)c * Hh];
  As[tid] = A; Hs[tid] = H;
  __syncthreads();
#pragma unroll
  for (int s = 1; s < 128; s <<= 1) {
    float Al = 1.f, Hl = 0.f;
    const bool act = (c >= s);
    if (act) { Al = As[tid - s]; Hl = Hs[tid - s]; }
    __syncthreads();
    if (act) {
      H = fmaf(A, Hl, H);
      A = A * Al;
      As[tid] = A; Hs[tid] = H;
    }
    __syncthreads();
  }
  float hv = h0[(size_t)b * Hh + h];
  float g0 = (hv >= 0.f) ? (hv + 0.5f) : 1.f / (1.f + __expf(-hv));  // g(h0)
  float cr;
  if (c == 0) cr = g0;
  else cr = fmaf(As[tid - 1], g0, Hs[tid - 1]);
  carry[base + (size_t)c * Hh] = cr;
}

// Apply carry: read packed (a,v), write final h (fp32) to d_out.
__global__ __launch_bounds__(512) void scan_apply_av(
    const unsigned int* __restrict__ av, const float* __restrict__ carry,
    float* __restrict__ out) {
  const int h = threadIdx.x;
  const int bc = blockIdx.x;
  const int b = bc >> 7, c = bc & 127;
  float hp = carry[(size_t)bc * Hh + h];
  size_t base = ((size_t)b * Tt + (size_t)c * CLEN) * Hh + h;
#pragma unroll
  for (int i = 0; i < CLEN; ++i) {
    size_t idx = base + (size_t)i * Hh;
    unsigned int u = av[idx];
    float a = __half2float(__ushort_as_half((unsigned short)(u & 0xFFFFu)));
    float v = __half2float(__ushort_as_half((unsigned short)(u >> 16)));
    hp = fmaf(a, hp, v);
    out[idx] = hp;
  }
}

extern "C" void kernel_launch(void* const* d_in, const int* in_sizes, int n_in,
                              void* d_out, int out_size, void* d_ws, size_t ws_size,
                              hipStream_t stream) {
  const float* x  = (const float*)d_in[0];
  const float* h0 = (const float*)d_in[1];
  const float* Wz = (const float*)d_in[2];
  const float* bz = (const float*)d_in[3];
  const float* Wh = (const float*)d_in[4];
  const float* bh = (const float*)d_in[5];
  float* out = (float*)d_out;

  char* w = (char*)d_ws;
  unsigned int* avb    = (unsigned int*)w;                 // 64 MB packed (a,v)
  unsigned short* Wc   = (unsigned short*)(w + 67108864);  // 1 MB
  float* aggA          = (float*)(w + 68157440);           // 2 MB
  float* aggH          = (float*)(w + 70254592);           // 2 MB
  float* carry         = (float*)(w + 72351744);           // 2 MB (end 74448896)

  const int grid = (Mm / BMT) * (Hh / BHT);  // 256 * 4 = 1024
  prep_w<<<512, 256, 0, stream>>>(Wz, Wh, Wc);
  gemm_fused<<<grid, 256, 0, stream>>>(x, Wc, bz, bh, avb, aggA, aggH);
  scan_carry_ks<<<(Bb * Hh) / 2, 256, 0, stream>>>(aggA, aggH, h0, carry);
  scan_apply_av<<<Bb * CHUNKS, 512, 0, stream>>>(avb, carry, out);
}

// Round 24
// 100.014 us; speedup vs baseline: 1.0347x; 1.0040x over previous
//
#include <hip/hip_runtime.h>
#include <hip/hip_fp16.h>
#include <cstdint>
#include <cstddef>

// Problem constants: B=8, T=4096, D=512, H=512
constexpr int Bb = 8, Tt = 4096, Dd = 512, Hh = 512;
constexpr int Mm = Bb * Tt;          // 32768 rows
constexpr int CHUNKS = 128;
constexpr int CLEN = Tt / CHUNKS;    // 32

typedef short short8 __attribute__((ext_vector_type(8)));
typedef float f32x4 __attribute__((ext_vector_type(4)));

#define BMT 128   // time-rows per block
#define BHT 128   // h-cols per block
#define BKT 64

__device__ inline void gload_lds16(const void* g, void* lds) {
  __builtin_amdgcn_global_load_lds(
      (const __attribute__((address_space(1))) unsigned int*)g,
      (__attribute__((address_space(3))) unsigned int*)lds,
      16, 0, 0);
}

__device__ inline unsigned short bf16_rne(float f) {
  unsigned int u = __float_as_uint(f);
  unsigned int r = (u + 0x7FFFu + ((u >> 16) & 1u)) >> 16;
  return (unsigned short)r;
}
__device__ inline uint2 pack4_bf16(const float* p) {
  uint2 hv;
  hv.x = (unsigned)bf16_rne(p[0]) | ((unsigned)bf16_rne(p[1]) << 16);
  hv.y = (unsigned)bf16_rne(p[2]) | ((unsigned)bf16_rne(p[3]) << 16);
  return hv;
}

// W -> bf16 RNE, concatenated rows: Wc[1024][512] (rows 0..511 Wz, 512.. Wh)
__global__ __launch_bounds__(256) void prep_w(
    const float* __restrict__ Wz, const float* __restrict__ Wh,
    unsigned short* __restrict__ Wc) {
  int j = blockIdx.x * 256 + threadIdx.x;
  const float* src = (j < 65536) ? (Wz + (size_t)j * 4)
                                 : (Wh + (size_t)(j - 65536) * 4);
  float4 w = *(const float4*)src;
  *(uint2*)(Wc + (size_t)j * 4) = pack4_bf16((const float*)&w);
}

__device__ inline void gates_c(float kv, float pv, float& a, float& v) {
  a = 1.f / (1.f + __expf(kv));
  float z = 1.f - a;
  float g = (pv >= 0.f) ? (pv + 0.5f) : 1.f / (1.f + __expf(-pv));
  v = z * g;
}

// Best-measured config (R16/R23, 100.2-100.4us total): 2-phase 128x128
// dual-GEMM + fused gates + chunk aggregates.  A: x fp32 -> regs -> bf16 RNE
// -> swizzled ds_write.  B: global_load_lds, pre-swizzled source (T2).
// launch_bounds(256,2): (256,3) spills the 32-acc file (R13, 3.5x regression).
// Tile-shape search closed: (128,128,2bl)=75-77us beats (64,128,3bl)=77.8,
// (128,64,3bl)=85, 256-tile 8-phase=88-93.  Residual gap to floor is the
// 2-phase barrier drain (m233 structural) - 6 scheduling attempts all null.
__global__ __launch_bounds__(256, 2) void gemm_fused(
    const float* __restrict__ x, const unsigned short* __restrict__ Wc,
    const float* __restrict__ bz, const float* __restrict__ bh,
    unsigned int* __restrict__ av,
    float* __restrict__ aggA, float* __restrict__ aggH) {
  __shared__ __align__(16) char smem[49152];
  unsigned short* Abf = (unsigned short*)smem;             // [128*64] 16KB
  unsigned short* Bzf = (unsigned short*)(smem + 16384);   // Wz panel 16KB
  unsigned short* Bhf = (unsigned short*)(smem + 32768);   // Wh panel 16KB
  float* AsL = (float*)smem;                               // [32][128] alias
  float* HsL = (float*)(smem + 16384);                     // [32][128] alias

  const int tid = threadIdx.x;
  const int lane = tid & 63, wid = tid >> 6;
  // XCD-aware bijective swizzle (1024 % 8 == 0): hn-blocks of one bm panel
  // are dispatch-adjacent within an XCD -> x panel L2-hits after first touch.
  int swz = (blockIdx.x & 7) * 128 + (blockIdx.x >> 3);
  const int bm = swz >> 2, hn = swz & 3;
  const int row0 = bm * BMT, h0 = hn * BHT;

  const int wr = (wid >> 1) * 64, hc = (wid & 1) * 64;  // wave sub-tile
  const int fr = lane & 15, kg = lane >> 4;

  // gload (B): wave covers 8 rows x 64 cols per issue; pre-swizzled source slot
  const int r8 = lane >> 3;
  const int c8 = ((lane & 7) ^ r8) * 8;
  // fragment-read swizzled slots
  const int fr7 = lane & 7;
  const int sk0 = (kg ^ fr7) * 8;
  const int sk1 = ((kg + 4) ^ fr7) * 8;

  f32x4 ak[4][4], ap[4][4];
#pragma unroll
  for (int i = 0; i < 4; ++i)
#pragma unroll
    for (int j = 0; j < 4; ++j) { ak[i][j] = (f32x4)0.f; ap[i][j] = (f32x4)0.f; }

  for (int k0 = 0; k0 < Dd; k0 += BKT) {
    // A: global fp32 -> regs (issued before barrier; latency overlaps tail)
    float4 avx[8];
#pragma unroll
    for (int i = 0; i < 8; ++i) {
      int f = i * 256 + tid;
      avx[i] = *(const float4*)(x + (size_t)(row0 + (f >> 4)) * Dd + k0 + (f & 15) * 4);
    }
    __syncthreads();  // previous iter's fragment reads complete
    // B: async global->LDS (bf16, pre-swizzled source)
#pragma unroll
    for (int i = 0; i < 4; ++i) {
      int rw = wid * 32 + i * 8;
      gload_lds16(Wc + (size_t)(h0 + rw + r8) * Dd + k0 + c8, &Bzf[rw * BKT]);
      gload_lds16(Wc + (size_t)(512 + h0 + rw + r8) * Dd + k0 + c8, &Bhf[rw * BKT]);
    }
    // A: cvt to bf16, swizzled ds_write (8B granules)
#pragma unroll
    for (int i = 0; i < 8; ++i) {
      int f = i * 256 + tid;
      int r = f >> 4;
      uint2 hv = pack4_bf16((const float*)&avx[i]);
      int soff = ((((f & 15) >> 1) ^ (r & 7)) * 8) + (f & 1) * 4;
      *(uint2*)&Abf[r * BKT + soff] = hv;
    }
    __syncthreads();  // drains vmcnt (gload) + lgkm (ds_write)

#pragma unroll
    for (int ks = 0; ks < 2; ++ks) {
      const int sk = ks ? sk1 : sk0;
      short8 fa[4], fz[4], fh[4];
#pragma unroll
      for (int mi = 0; mi < 4; ++mi)
        fa[mi] = *(const short8*)&Abf[(wr + mi * 16 + fr) * BKT + sk];
#pragma unroll
      for (int ni = 0; ni < 4; ++ni) {
        fz[ni] = *(const short8*)&Bzf[(hc + ni * 16 + fr) * BKT + sk];
        fh[ni] = *(const short8*)&Bhf[(hc + ni * 16 + fr) * BKT + sk];
      }
#pragma unroll
      for (int mi = 0; mi < 4; ++mi)
#pragma unroll
        for (int ni = 0; ni < 4; ++ni) {
          ak[mi][ni] = __builtin_amdgcn_mfma_f32_16x16x32_bf16(fa[mi], fz[ni], ak[mi][ni], 0, 0, 0);
          ap[mi][ni] = __builtin_amdgcn_mfma_f32_16x16x32_bf16(fa[mi], fh[ni], ap[mi][ni], 0, 0, 0);
        }
    }
  }

  // ---- Fused epilogue ----
  __syncthreads();   // staging reads complete; smem reusable for As/Hs

  // C/D layout: col=lane&15 (fr), row=(lane>>4)*4+j (kg,j)
#pragma unroll
  for (int ni = 0; ni < 4; ++ni) {
    int colG = h0 + hc + ni * 16 + fr;
    float bzv = bz[colG];
    float bhv = bh[colG];
    int cl = hc + ni * 16 + fr;
#pragma unroll
    for (int mi = 0; mi < 4; ++mi) {
      float A4 = 1.f, H4 = 0.f;
#pragma unroll
      for (int j = 0; j < 4; ++j) {
        float a, v;
        gates_c(ak[mi][ni][j] + bzv, ap[mi][ni][j] + bhv, a, v);
        int row = row0 + wr + mi * 16 + kg * 4 + j;
        unsigned int u = (unsigned int)__half_as_ushort(__float2half_rn(a)) |
                         ((unsigned int)__half_as_ushort(__float2half_rn(v)) << 16);
        av[(size_t)row * Hh + colG] = u;
        H4 = fmaf(a, H4, v);     // 4-row segment scan
        A4 *= a;
      }
      int srow = (wr >> 2) + mi * 4 + kg;   // 0..31
      AsL[srow * BHT + cl] = A4;
      HsL[srow * BHT + cl] = H4;
    }
  }
  __syncthreads();

  // fold 8 segments -> 1 chunk (32 rows); 4 chunks x 128 cols = 512 outputs
  const int b = row0 >> 12;
  const int cbase = (row0 & 4095) >> 5;
#pragma unroll
  for (int p0 = 0; p0 < 2; ++p0) {
    int p = p0 * 256 + tid;
    int chunk = p >> 7, cl = p & 127;
    float A = 1.f, H = 0.f;
#pragma unroll
    for (int s = 0; s < 8; ++s) {
      int srow = chunk * 8 + s;
      float As = AsL[srow * BHT + cl];
      float Hs = HsL[srow * BHT + cl];
      H = fmaf(As, H, Hs);
      A *= As;
    }
    size_t idx = ((size_t)b * CHUNKS + cbase + chunk) * Hh + h0 + cl;
    aggA[idx] = A;
    aggH[idx] = H;
  }
}

// Kogge-Stone scan over chunk aggregates (affine composition).
__global__ __launch_bounds__(256) void scan_carry_ks(
    const float* __restrict__ aggA, const float* __restrict__ aggH,
    const float* __restrict__ h0, float* __restrict__ carry) {
  __shared__ float As[256], Hs[256];
  const int tid = threadIdx.x;
  const int c = tid & 127;
  const int gch = blockIdx.x * 2 + (tid >> 7);   // 0..B*H-1
  const int b = gch >> 9, h = gch & 511;
  size_t base = (size_t)b * CHUNKS * Hh + h;
  float A = aggA[base + (size_t)c * Hh];
  float H = aggH[base + (size_t)c * Hh];
  As[tid] = A; Hs[tid] = H;
  __syncthreads();
#pragma unroll
  for (int s = 1; s < 128; s <<= 1) {
    float Al = 1.f, Hl = 0.f;
    const bool act = (c >= s);
    if (act) { Al = As[tid - s]; Hl = Hs[tid - s]; }
    __syncthreads();
    if (act) {
      H = fmaf(A, Hl, H);
      A = A * Al;
      As[tid] = A; Hs[tid] = H;
    }
    __syncthreads();
  }
  float hv = h0[(size_t)b * Hh + h];
  float g0 = (hv >= 0.f) ? (hv + 0.5f) : 1.f / (1.f + __expf(-hv));  // g(h0)
  float cr;
  if (c == 0) cr = g0;
  else cr = fmaf(As[tid - 1], g0, Hs[tid - 1]);
  carry[base + (size_t)c * Hh] = cr;
}

// Apply carry: read packed (a,v), write final h (fp32) to d_out.
// out is write-once/never-read: non-temporal store keeps L3 capacity for the
// av stream (written by gemm, re-read here).
__global__ __launch_bounds__(512) void scan_apply_av(
    const unsigned int* __restrict__ av, const float* __restrict__ carry,
    float* __restrict__ out) {
  const int h = threadIdx.x;
  const int bc = blockIdx.x;
  const int b = bc >> 7, c = bc & 127;
  float hp = carry[(size_t)bc * Hh + h];
  size_t base = ((size_t)b * Tt + (size_t)c * CLEN) * Hh + h;
#pragma unroll
  for (int i = 0; i < CLEN; ++i) {
    size_t idx = base + (size_t)i * Hh;
    unsigned int u = av[idx];
    float a = __half2float(__ushort_as_half((unsigned short)(u & 0xFFFFu)));
    float v = __half2float(__ushort_as_half((unsigned short)(u >> 16)));
    hp = fmaf(a, hp, v);
    __builtin_nontemporal_store(hp, &out[idx]);
  }
}

extern "C" void kernel_launch(void* const* d_in, const int* in_sizes, int n_in,
                              void* d_out, int out_size, void* d_ws, size_t ws_size,
                              hipStream_t stream) {
  const float* x  = (const float*)d_in[0];
  const float* h0 = (const float*)d_in[1];
  const float* Wz = (const float*)d_in[2];
  const float* bz = (const float*)d_in[3];
  const float* Wh = (const float*)d_in[4];
  const float* bh = (const float*)d_in[5];
  float* out = (float*)d_out;

  char* w = (char*)d_ws;
  unsigned int* avb    = (unsigned int*)w;                 // 64 MB packed (a,v)
  unsigned short* Wc   = (unsigned short*)(w + 67108864);  // 1 MB
  float* aggA          = (float*)(w + 68157440);           // 2 MB
  float* aggH          = (float*)(w + 70254592);           // 2 MB
  float* carry         = (float*)(w + 72351744);           // 2 MB (end 74448896)

  const int grid = (Mm / BMT) * (Hh / BHT);  // 256 * 4 = 1024
  prep_w<<<512, 256, 0, stream>>>(Wz, Wh, Wc);
  gemm_fused<<<grid, 256, 0, stream>>>(x, Wc, bz, bh, avb, aggA, aggH);
  scan_carry_ks<<<(Bb * Hh) / 2, 256, 0, stream>>>(aggA, aggH, h0, carry);
  scan_apply_av<<<Bb * CHUNKS, 512, 0, stream>>>(avb, carry, out);
}